// Round 1
// baseline (44.046 us; speedup 1.0000x reference)
//
#include <hip/hip_runtime.h>
#include <hip/hip_bf16.h>

typedef __attribute__((ext_vector_type(8))) short bf16x8;
typedef __attribute__((ext_vector_type(4))) float f32x4;

#define N_PTS  500000
#define DIM    64
#define NCLUST 128
#define TILES  (N_PTS / 16)   // 31250, exact (no tail)

static __device__ __forceinline__ unsigned short f2bf(float x) {
    union { float f; unsigned u; } un; un.f = x;
    unsigned u = un.u;
    u += 0x7fffu + ((u >> 16) & 1u);   // round-to-nearest-even
    return (unsigned short)(u >> 16);
}

static __device__ __forceinline__ float sq4(float4 v) {
    return v.x*v.x + v.y*v.y + v.z*v.z + v.w*v.w;
}

__global__ __launch_bounds__(256) void kmeans_lse_kernel(
    const float* __restrict__ X, const float* __restrict__ centers,
    const float* __restrict__ vars_, const float* __restrict__ prs,
    const float* __restrict__ threshold, float* __restrict__ out)
{
    // Scaled centers (c/var) as bf16 + per-cluster LSE constants.
    __shared__ unsigned short sC[NCLUST][DIM];   // 16 KB
    __shared__ float sA[NCLUST];                 // a_j = -0.5/var_j
    __shared__ float sB[NCLUST];                 // b_j = a_j*c2_j + ln(prs_j)

    const int tid = threadIdx.x;
    if (tid < NCLUST) {
        const int j = tid;
        const float inv = 1.0f / vars_[j];
        float c2 = 0.0f;
        #pragma unroll
        for (int k = 0; k < DIM; k += 4) {
            float4 c = *(const float4*)(centers + j*DIM + k);
            c2 = fmaf(c.x, c.x, fmaf(c.y, c.y, fmaf(c.z, c.z, fmaf(c.w, c.w, c2))));
            sC[j][k+0] = f2bf(c.x * inv);
            sC[j][k+1] = f2bf(c.y * inv);
            sC[j][k+2] = f2bf(c.z * inv);
            sC[j][k+3] = f2bf(c.w * inv);
        }
        const float a = -0.5f * inv;
        sA[j] = a;
        sB[j] = fmaf(a, c2, __logf(prs[j]));
    }
    __syncthreads();

    const int lane = tid & 63;
    const int wid  = tid >> 6;
    const int g    = lane >> 4;   // k-group (0..3)
    const int r    = lane & 15;   // row (A: point-in-tile) / col (B: cluster-in-tile)

    // Hoist B fragments + per-cluster constants into registers for the whole loop.
    // k-mapping convention (consistent A/B bijection): slot e of group g = k 8g+e.
    bf16x8 Bf[8][2];
    float Aco[8], Bco[8];
    #pragma unroll
    for (int t = 0; t < 8; ++t) {
        Bf[t][0] = *(const bf16x8*)&sC[16*t + r][ 8*g];
        Bf[t][1] = *(const bf16x8*)&sC[16*t + r][32 + 8*g];
        Aco[t] = sA[16*t + r];
        Bco[t] = sB[16*t + r];
    }
    const float thr = threshold[0];

    for (int tile = blockIdx.x*4 + wid; tile < TILES; tile += gridDim.x*4) {
        // Each lane: row r of the 16-point tile, 8 floats per k-half. 4x dwordx4.
        const float* xrow = X + (size_t)(tile*16 + r) * DIM;
        float4 x0 = *(const float4*)(xrow + 8*g);
        float4 x1 = *(const float4*)(xrow + 8*g + 4);
        float4 x2v= *(const float4*)(xrow + 32 + 8*g);
        float4 x3 = *(const float4*)(xrow + 32 + 8*g + 4);

        // ||x||^2 in fp32: partial per lane, reduce across the 4 k-groups.
        float ss = sq4(x0) + sq4(x1) + sq4(x2v) + sq4(x3);
        ss += __shfl_xor(ss, 16);
        ss += __shfl_xor(ss, 32);

        // Pack A fragments (fp32 -> bf16, RNE).
        bf16x8 A0, A1;
        A0[0]=(short)f2bf(x0.x); A0[1]=(short)f2bf(x0.y); A0[2]=(short)f2bf(x0.z); A0[3]=(short)f2bf(x0.w);
        A0[4]=(short)f2bf(x1.x); A0[5]=(short)f2bf(x1.y); A0[6]=(short)f2bf(x1.z); A0[7]=(short)f2bf(x1.w);
        A1[0]=(short)f2bf(x2v.x);A1[1]=(short)f2bf(x2v.y);A1[2]=(short)f2bf(x2v.z);A1[3]=(short)f2bf(x2v.w);
        A1[4]=(short)f2bf(x3.x); A1[5]=(short)f2bf(x3.y); A1[6]=(short)f2bf(x3.z); A1[7]=(short)f2bf(x3.w);

        // cross' = (X @ C^T)/var : 8 cluster-tiles x 2 K-halves.
        f32x4 acc[8];
        #pragma unroll
        for (int t = 0; t < 8; ++t) {
            acc[t] = (f32x4){0.f, 0.f, 0.f, 0.f};
            acc[t] = __builtin_amdgcn_mfma_f32_16x16x32_bf16(A0, Bf[t][0], acc[t], 0, 0, 0);
            acc[t] = __builtin_amdgcn_mfma_f32_16x16x32_bf16(A1, Bf[t][1], acc[t], 0, 0, 0);
        }

        // D layout: col = lane&15 (cluster), row = 4*g + q (point). Need x2 of rows 4g+q.
        float x2q[4];
        #pragma unroll
        for (int q = 0; q < 4; ++q) x2q[q] = __shfl(ss, 4*g + q, 64);

        // Weighted LSE over 128 clusters: per-lane 8, then 16-lane butterfly.
        float m[4] = {-1e30f, -1e30f, -1e30f, -1e30f};
        #pragma unroll
        for (int t = 0; t < 8; ++t)
            #pragma unroll
            for (int q = 0; q < 4; ++q) {
                float tv = acc[t][q] + fmaf(Aco[t], x2q[q], Bco[t]);
                m[q] = fmaxf(m[q], tv);
            }
        #pragma unroll
        for (int q = 0; q < 4; ++q) {
            m[q] = fmaxf(m[q], __shfl_xor(m[q], 1));
            m[q] = fmaxf(m[q], __shfl_xor(m[q], 2));
            m[q] = fmaxf(m[q], __shfl_xor(m[q], 4));
            m[q] = fmaxf(m[q], __shfl_xor(m[q], 8));
        }
        float s[4] = {0.f, 0.f, 0.f, 0.f};
        #pragma unroll
        for (int t = 0; t < 8; ++t)
            #pragma unroll
            for (int q = 0; q < 4; ++q) {
                float tv = acc[t][q] + fmaf(Aco[t], x2q[q], Bco[t]);  // recompute: saves 32 VGPRs
                s[q] += __expf(tv - m[q]);
            }
        #pragma unroll
        for (int q = 0; q < 4; ++q) {
            s[q] += __shfl_xor(s[q], 1);
            s[q] += __shfl_xor(s[q], 2);
            s[q] += __shfl_xor(s[q], 4);
            s[q] += __shfl_xor(s[q], 8);
        }

        // Lanes 16g+q (q<4) write row 4g+q: 16 rows, each exactly once.
        if (r < 4) {
            out[tile*16 + 4*g + r] = m[r] + __logf(s[r]) - thr;
        }
    }
}

extern "C" void kernel_launch(void* const* d_in, const int* in_sizes, int n_in,
                              void* d_out, int out_size, void* d_ws, size_t ws_size,
                              hipStream_t stream) {
    const float* X         = (const float*)d_in[0];
    const float* centers   = (const float*)d_in[1];
    const float* vars_     = (const float*)d_in[2];
    const float* prs       = (const float*)d_in[3];
    const float* threshold = (const float*)d_in[4];
    float* out = (float*)d_out;
    (void)in_sizes; (void)n_in; (void)out_size; (void)d_ws; (void)ws_size;

    kmeans_lse_kernel<<<1024, 256, 0, stream>>>(X, centers, vars_, prs, threshold, out);
}

// Round 2
// 38.736 us; speedup vs baseline: 1.1371x; 1.1371x over previous
//
#include <hip/hip_runtime.h>
#include <hip/hip_bf16.h>

typedef __attribute__((ext_vector_type(8))) short bf16x8;
typedef __attribute__((ext_vector_type(4))) float f32x4;

#define N_PTS  500000
#define DIM    64
#define NCLUST 128
#define TILES  (N_PTS / 16)   // 31250, exact (no tail)
#define NBLK   512            // 2 blocks/CU resident at ~190 VGPR
#define LOG2E  1.44269504088896f
#define LN2    0.69314718055994f

static __device__ __forceinline__ unsigned short f2bf(float x) {
    union { float f; unsigned u; } un; un.f = x;
    unsigned u = un.u;
    u += 0x7fffu + ((u >> 16) & 1u);   // round-to-nearest-even
    return (unsigned short)(u >> 16);
}

static __device__ __forceinline__ float sq4(float4 v) {
    return v.x*v.x + v.y*v.y + v.z*v.z + v.w*v.w;
}

static __device__ __forceinline__ bf16x8 pack8(float4 a, float4 b) {
    union { bf16x8 v; __hip_bfloat162 h[4]; } u;
    u.h[0] = __float22bfloat162_rn(make_float2(a.x, a.y));
    u.h[1] = __float22bfloat162_rn(make_float2(a.z, a.w));
    u.h[2] = __float22bfloat162_rn(make_float2(b.x, b.y));
    u.h[3] = __float22bfloat162_rn(make_float2(b.z, b.w));
    return u.v;
}

__global__ __launch_bounds__(256) void kmeans_lse_kernel(
    const float* __restrict__ X, const float* __restrict__ centers,
    const float* __restrict__ vars_, const float* __restrict__ prs,
    const float* __restrict__ threshold, float* __restrict__ out)
{
    // log2-domain constants: t~_ij = log2e * logit_ij
    //   scaled centers c'_j = c_j * (1/var_j) * log2e   (MFMA yields cross term directly)
    //   sA_j = -0.5/var_j * log2e,  sB_j = sA_j*||c_j||^2 + log2(prs_j)
    __shared__ unsigned short sC[NCLUST][DIM];   // 16 KB, bf16 scaled centers
    __shared__ float sA[NCLUST];
    __shared__ float sB[NCLUST];

    const int tid = threadIdx.x;
    if (tid < NCLUST) {
        const int j = tid;
        const float inv = 1.0f / vars_[j];
        const float cscale = inv * LOG2E;
        float c2 = 0.0f;
        #pragma unroll
        for (int k = 0; k < DIM; k += 4) {
            float4 c = *(const float4*)(centers + j*DIM + k);
            c2 = fmaf(c.x, c.x, fmaf(c.y, c.y, fmaf(c.z, c.z, fmaf(c.w, c.w, c2))));
            sC[j][k+0] = f2bf(c.x * cscale);
            sC[j][k+1] = f2bf(c.y * cscale);
            sC[j][k+2] = f2bf(c.z * cscale);
            sC[j][k+3] = f2bf(c.w * cscale);
        }
        const float a = -0.5f * inv * LOG2E;
        sA[j] = a;
        sB[j] = fmaf(a, c2, __log2f(prs[j]));
    }
    __syncthreads();

    const int lane = tid & 63;
    const int wid  = tid >> 6;
    const int g    = lane >> 4;   // k-group (0..3)
    const int r    = lane & 15;   // row (A: point) / col (B: cluster)

    // B fragments + per-cluster constants live in registers for the whole loop.
    bf16x8 Bf[8][2];
    float Aco[8], Bco[8];
    #pragma unroll
    for (int t = 0; t < 8; ++t) {
        Bf[t][0] = *(const bf16x8*)&sC[16*t + r][ 8*g];
        Bf[t][1] = *(const bf16x8*)&sC[16*t + r][32 + 8*g];
        Aco[t] = sA[16*t + r];
        Bco[t] = sB[16*t + r];
    }
    const float thr = threshold[0];

    const int S = NBLK * 4;                 // grid stride in tiles (2048)
    int tile = blockIdx.x*4 + wid;
    const size_t lane_off = (size_t)r * DIM + 8*g;

    // --- depth-2 software pipeline: cur / next / next-next register sets ---
    const float* pc = X + (size_t)tile*16*DIM + lane_off;
    float4 c0 = *(const float4*)(pc),    c1 = *(const float4*)(pc+4),
           c2v= *(const float4*)(pc+32), c3 = *(const float4*)(pc+36);
    float4 n0{}, n1{}, n2{}, n3{}, m0{}, m1{}, m2{}, m3{};
    int nt = tile + S;
    if (nt < TILES) {
        const float* pn = X + (size_t)nt*16*DIM + lane_off;
        n0 = *(const float4*)(pn);    n1 = *(const float4*)(pn+4);
        n2 = *(const float4*)(pn+32); n3 = *(const float4*)(pn+36);
    }

    for (;;) {
        const int t2 = nt + S;
        if (t2 < TILES) {               // prefetch tile+2S (wave-uniform branch)
            const float* pm = X + (size_t)t2*16*DIM + lane_off;
            m0 = *(const float4*)(pm);    m1 = *(const float4*)(pm+4);
            m2 = *(const float4*)(pm+32); m3 = *(const float4*)(pm+36);
        }

        // ||x||^2 (fp32), reduce across the 4 k-groups
        float ss = sq4(c0) + sq4(c1) + sq4(c2v) + sq4(c3);
        ss += __shfl_xor(ss, 16);
        ss += __shfl_xor(ss, 32);

        bf16x8 A0 = pack8(c0, c1);
        bf16x8 A1 = pack8(c2v, c3);

        f32x4 acc[8];
        #pragma unroll
        for (int t = 0; t < 8; ++t) {
            acc[t] = (f32x4){0.f, 0.f, 0.f, 0.f};
            acc[t] = __builtin_amdgcn_mfma_f32_16x16x32_bf16(A0, Bf[t][0], acc[t], 0, 0, 0);
            acc[t] = __builtin_amdgcn_mfma_f32_16x16x32_bf16(A1, Bf[t][1], acc[t], 0, 0, 0);
        }

        // D layout: col = lane&15 (cluster), row = 4*g + q (point)
        float x2q[4];
        #pragma unroll
        for (int q = 0; q < 4; ++q) x2q[q] = __shfl(ss, 4*g + q, 64);

        // t~ in place; running max
        float mx[4] = {-1e30f, -1e30f, -1e30f, -1e30f};
        #pragma unroll
        for (int t = 0; t < 8; ++t)
            #pragma unroll
            for (int q = 0; q < 4; ++q) {
                acc[t][q] += fmaf(Aco[t], x2q[q], Bco[t]);
                mx[q] = fmaxf(mx[q], acc[t][q]);
            }
        #pragma unroll
        for (int q = 0; q < 4; ++q) {
            mx[q] = fmaxf(mx[q], __shfl_xor(mx[q], 1));
            mx[q] = fmaxf(mx[q], __shfl_xor(mx[q], 2));
            mx[q] = fmaxf(mx[q], __shfl_xor(mx[q], 4));
            mx[q] = fmaxf(mx[q], __shfl_xor(mx[q], 8));
        }
        float sm[4] = {0.f, 0.f, 0.f, 0.f};
        #pragma unroll
        for (int t = 0; t < 8; ++t)
            #pragma unroll
            for (int q = 0; q < 4; ++q)
                sm[q] += __builtin_amdgcn_exp2f(acc[t][q] - mx[q]);   // raw v_exp_f32
        #pragma unroll
        for (int q = 0; q < 4; ++q) {
            sm[q] += __shfl_xor(sm[q], 1);
            sm[q] += __shfl_xor(sm[q], 2);
            sm[q] += __shfl_xor(sm[q], 4);
            sm[q] += __shfl_xor(sm[q], 8);
        }

        // lanes 16g+r (r<4) write row 4g+r: 16 rows, each exactly once
        if (r < 4) {
            out[tile*16 + 4*g + r] =
                fmaf(mx[r] + __builtin_amdgcn_logf(sm[r]), LN2, -thr);  // v_log_f32 = log2
        }

        if (nt >= TILES) break;
        tile = nt; nt = t2;
        c0 = n0; c1 = n1; c2v = n2; c3 = n3;
        n0 = m0; n1 = m1; n2 = m2; n3 = m3;
    }
}

extern "C" void kernel_launch(void* const* d_in, const int* in_sizes, int n_in,
                              void* d_out, int out_size, void* d_ws, size_t ws_size,
                              hipStream_t stream) {
    const float* X         = (const float*)d_in[0];
    const float* centers   = (const float*)d_in[1];
    const float* vars_     = (const float*)d_in[2];
    const float* prs       = (const float*)d_in[3];
    const float* threshold = (const float*)d_in[4];
    float* out = (float*)d_out;
    (void)in_sizes; (void)n_in; (void)out_size; (void)d_ws; (void)ws_size;

    kmeans_lse_kernel<<<NBLK, 256, 0, stream>>>(X, centers, vars_, prs, threshold, out);
}